// Round 10
// baseline (355.064 us; speedup 1.0000x reference)
//
#include <hip/hip_runtime.h>

#define NQ 19
#define SZ (1u << 19)
#define NBLK 256u

struct Params {
    const int* ei;
    const float* state; const float* mass; const float* spin; const float* charge;
    const float* p_norm; const float* theta;
    const float* gnw; const float* gnb; const float* gew; const float* geb;
    const float* nw; const float* nb; const float* ew; const float* eb;
    const float* qw;
    float2* buf0; float2* buf1;
    double* partial;
    unsigned* ctr;
    float* out;
};

// Grid barrier with cross-XCD coherence: __syncthreads drains this block's
// vmem; t0 release-fences (L2 writeback), arrives, spins (agent-scope
// relaxed), acquire-fences (L2 invalidate). Every block fences, so every
// XCD's L2 is covered. r7 (cg) proved fence-based coherence of cached data
// works on this chip; r9 proved this spin structure is correct & cheap.
__device__ __forceinline__ void gridbar(unsigned* ctr, unsigned target)
{
    __syncthreads();
    if (threadIdx.x == 0) {
        __threadfence();                               // release: wb L2
        __hip_atomic_fetch_add(ctr, 1u, __ATOMIC_RELAXED,
                               __HIP_MEMORY_SCOPE_AGENT);
        while (__hip_atomic_load(ctr, __ATOMIC_RELAXED,
                                 __HIP_MEMORY_SCOPE_AGENT) < target)
            __builtin_amdgcn_s_sleep(1);
        __threadfence();                               // acquire: inv L2/L1
    }
    __syncthreads();
}

// Ring permutation inverse (bit space):
//   b = (c ^ (c>>1)) & 0x1FFFF ; b17 = c0^c17^c18 ; b18 = c0^c18
// Bits >=11 of pinv(c) depend ONLY on c0 and c bits 11..18.
__device__ __forceinline__ unsigned pinv(unsigned c)
{
    unsigned y = (c ^ (c >> 1)) & 0x1FFFFu;
    unsigned c0 = c & 1u, c17 = (c >> 17) & 1u, c18 = (c >> 18) & 1u;
    return y | ((c0 ^ c17 ^ c18) << 17) | ((c0 ^ c18) << 18);
}

// Padded LDS index: +2 float2 per 8 (keeps 8-groups intact; float4-safe).
__device__ __forceinline__ unsigned padl(unsigned l) { return l + 2u * (l >> 3); }

__device__ __forceinline__ void bfly(float2& a, float2& b,
                                     float2 u00, float2 u01,
                                     float2 u10, float2 u11)
{
    float2 na, nb;
    na.x = u00.x * a.x - u00.y * a.y + u01.x * b.x - u01.y * b.y;
    na.y = u00.x * a.y + u00.y * a.x + u01.x * b.y + u01.y * b.x;
    nb.x = u10.x * a.x - u10.y * a.y + u11.x * b.x - u11.y * b.y;
    nb.y = u10.x * a.y + u10.y * a.x + u11.x * b.y + u11.y * b.x;
    a = na;
    b = nb;
}

__device__ __forceinline__ void apply_gates(float2 r[4], const float2* Gl,
                                            int ampbit0, int jbit0, int n)
{
    #pragma unroll
    for (int k = 0; k < n; ++k) {
        const float2 u00 = Gl[(ampbit0 + k) * 4 + 0];
        const float2 u01 = Gl[(ampbit0 + k) * 4 + 1];
        const float2 u10 = Gl[(ampbit0 + k) * 4 + 2];
        const float2 u11 = Gl[(ampbit0 + k) * 4 + 3];
        const int m = 1 << (jbit0 + k);
        #pragma unroll
        for (int j = 0; j < 4; ++j)
            if (!(j & m)) bfly(r[j], r[j | m], u00, u01, u10, u11);
    }
}

// Pass-A tail: gates on c bits 0..10 through the 6 register layouts
// (round-5/8-verified index math). X1 aliases the dead staging buffer.
__device__ __forceinline__ void passA_tail(float2 r[4], const float2* Gl,
                                           unsigned t, float2* X0, float2* X1)
{
    apply_gates(r, Gl, 0, 0, 2);
    *reinterpret_cast<float4*>(&X0[padl(t << 2)]) =
        make_float4(r[0].x, r[0].y, r[1].x, r[1].y);
    *reinterpret_cast<float4*>(&X0[padl((t << 2) + 2u)]) =
        make_float4(r[2].x, r[2].y, r[3].x, r[3].y);
    __syncthreads();
    #pragma unroll
    for (int j = 0; j < 4; ++j)
        r[j] = X0[padl((t & 3u) | ((unsigned)j << 2) | ((t >> 2) << 4))];
    apply_gates(r, Gl, 2, 0, 2);
    #pragma unroll
    for (int j = 0; j < 4; ++j)
        X1[padl((t & 3u) | ((unsigned)j << 2) | ((t >> 2) << 4))] = r[j];
    __syncthreads();
    #pragma unroll
    for (int j = 0; j < 4; ++j)
        r[j] = X1[padl((t & 15u) | ((unsigned)j << 4) | ((t >> 4) << 6))];
    apply_gates(r, Gl, 4, 0, 2);
    #pragma unroll
    for (int j = 0; j < 4; ++j)
        X0[padl((t & 15u) | ((unsigned)j << 4) | ((t >> 4) << 6))] = r[j];
    __syncthreads();
    #pragma unroll
    for (int j = 0; j < 4; ++j)
        r[j] = X0[padl((t & 63u) | ((unsigned)j << 6) | ((t >> 6) << 8))];
    apply_gates(r, Gl, 6, 0, 2);
    #pragma unroll
    for (int j = 0; j < 4; ++j)
        X1[padl((t & 63u) | ((unsigned)j << 6) | ((t >> 6) << 8))] = r[j];
    __syncthreads();
    #pragma unroll
    for (int j = 0; j < 4; ++j)
        r[j] = X1[padl((t & 255u) | ((unsigned)j << 8) | ((t >> 8) << 10))];
    apply_gates(r, Gl, 8, 0, 2);
    #pragma unroll
    for (int j = 0; j < 4; ++j)
        X0[padl((t & 255u) | ((unsigned)j << 8) | ((t >> 8) << 10))] = r[j];
    __syncthreads();
    #pragma unroll
    for (int j = 0; j < 4; ++j)
        r[j] = X0[padl(t | ((unsigned)j << 9))];
    apply_gates(r, Gl, 10, 1, 1);          // gate c10 = l10 = j bit1
}

// Pass-B gates on c bits 11..18 (tile l: l0..l2=c0..c2, l3..l10=c11..c18).
__device__ __forceinline__ void passB_gates(float2 r[4], const float2* Gl,
                                            unsigned t, float2* X0, float2* X1)
{
    apply_gates(r, Gl, 11, 0, 2);
    #pragma unroll
    for (int j = 0; j < 4; ++j)
        X0[padl((t & 7u) | ((unsigned)j << 3) | ((t >> 3) << 5))] = r[j];
    __syncthreads();
    #pragma unroll
    for (int j = 0; j < 4; ++j)
        r[j] = X0[padl((t & 31u) | ((unsigned)j << 5) | ((t >> 5) << 7))];
    apply_gates(r, Gl, 13, 0, 2);
    #pragma unroll
    for (int j = 0; j < 4; ++j)
        X1[padl((t & 31u) | ((unsigned)j << 5) | ((t >> 5) << 7))] = r[j];
    __syncthreads();
    #pragma unroll
    for (int j = 0; j < 4; ++j)
        r[j] = X1[padl((t & 127u) | ((unsigned)j << 7) | ((t >> 7) << 9))];
    apply_gates(r, Gl, 15, 0, 2);
    #pragma unroll
    for (int j = 0; j < 4; ++j)
        X0[padl((t & 127u) | ((unsigned)j << 7) | ((t >> 7) << 9))] = r[j];
    __syncthreads();
    #pragma unroll
    for (int j = 0; j < 4; ++j)
        r[j] = X0[padl(t | ((unsigned)j << 9))];
    apply_gates(r, Gl, 17, 0, 2);          // gates c17,c18 = l9,l10 = j bits
}

__global__ void k_init(unsigned* ctr) { *ctr = 0u; }

// ---------------------------------------------------------------------------
// Single persistent kernel: per-block prep (GCN fp64 -> feats; all 6 layers'
// gate matrices; FM phase tables in `stage`), then 12 phases separated by
// fence-based grid barriers. A_l: ring-gather + gates c0..c10 (block =
// c11..c18); B_l: gates c11..c18 in place (block = c3..c10); B_5 folds the
// final ring + <Z_0> into sign-twisted fp64 partials; block 0 sums at end.
// State traffic uses NORMAL cached vector loads/stores (coherence via the
// barrier's agent-scope fences).
// Qubit q <-> bit k = 18-q. Fused gate U = RZ(t)*RX(t), c=cos(t/2), s=sin(t/2):
//   u00=(c^2,-sc) u01=(-s^2,-cs) u10=(s^2,-cs) u11=(c^2,sc)
// ---------------------------------------------------------------------------
__global__ __launch_bounds__(512, 1)
void k_all(Params P)
{
    __shared__ __align__(16) float2 stage[5120];   // FM tables / staging; X1 alias
    __shared__ __align__(16) float2 X0[2560];
    __shared__ float2 shG[6 * NQ * 4];
    __shared__ double sm[512];
    __shared__ double sh_feats[NQ];
    __shared__ double sh_S;

    const unsigned t = threadIdx.x;
    const unsigned blk = blockIdx.x;
    const unsigned base = blk << 11;

    // ---- per-block prep ----
    if (t == 0) {
        double deg[8], dis[8], h[8], o1[8], he[8], o2[8];
        for (int v = 0; v < 8; ++v) deg[v] = 1.0;                 // self loops
        for (int e = 0; e < 8; ++e) deg[P.ei[8 + e]] += 1.0;
        for (int v = 0; v < 8; ++v) dis[v] = 1.0 / sqrt(deg[v]);
        for (int v = 0; v < 8; ++v) {
            double s = 0.0;
            for (int k = 0; k < 4; ++k)
                s += (double)P.state[v * 4 + k] * (double)P.gnw[k];
            h[v] = s;
        }
        for (int v = 0; v < 8; ++v) o1[v] = h[v] * dis[v] * dis[v] + (double)P.gnb[0];
        for (int e = 0; e < 8; ++e) {
            int s = P.ei[e], d = P.ei[8 + e];
            o1[d] += h[s] * dis[s] * dis[d];
        }
        for (int j = 0; j < 9; ++j) {
            double a = (double)P.nb[j];
            for (int v = 0; v < 8; ++v) a += o1[v] * (double)P.nw[v * 9 + j];
            sh_feats[j] = a;
        }
        for (int e = 0; e < 8; ++e)
            he[e] = (double)P.mass[e] * (double)P.gew[0]
                  + (double)P.spin[e] * (double)P.gew[1]
                  + (double)P.charge[e] * (double)P.gew[2];
        for (int v = 0; v < 8; ++v) o2[v] = he[v] * dis[v] * dis[v] + (double)P.geb[0];
        for (int e = 0; e < 8; ++e) {
            int s = P.ei[e], d = P.ei[8 + e];
            o2[d] += he[s] * dis[s] * dis[d];
        }
        for (int j = 0; j < 8; ++j) {
            double a = (double)P.eb[j];
            for (int v = 0; v < 8; ++v) a += o2[v] * (double)P.ew[v * 8 + j];
            sh_feats[9 + j] = a;
        }
        sh_feats[17] = (double)P.p_norm[0];
        sh_feats[18] = (double)P.theta[0];
        double S = 0.0;
        for (int q = 0; q < NQ; ++q) S += sh_feats[q];
        sh_S = S;
    }
    __syncthreads();

    // all 6 layers' gate matrices (layer l angle = qw[i,q,j], i=l/3, j=l%3)
    for (unsigned g = t; g < 6u * NQ; g += 512u) {
        int l = (int)(g / NQ), q = (int)(g % NQ);
        int i = l / 3, j = l % 3;
        double th = (double)P.qw[i * (NQ * 3) + q * 3 + j];
        double c = cos(0.5 * th), s = sin(0.5 * th);
        int k = 18 - q;
        float2* Ug = &shG[(l * NQ + k) * 4];
        Ug[0] = make_float2((float)(c * c), (float)(-s * c));
        Ug[1] = make_float2((float)(-s * s), (float)(-c * s));
        Ug[2] = make_float2((float)(s * s), (float)(-c * s));
        Ug[3] = make_float2((float)(c * c), (float)(s * c));
    }
    // FM phase tables in stage: phi(b) = sum_k feats[18-k]*b_k - S/2; amp in W1
    {
        double S = sh_S;
        for (unsigned m = t; m < 1024u; m += 512u) {
            double a = -0.5 * S;
            for (int k = 0; k < 10; ++k)
                if ((m >> k) & 1u) a += sh_feats[18 - k];
            double sp, cp;
            sincos(a, &sp, &cp);
            stage[m] = make_float2((float)cp, (float)sp);
        }
        const double amp = 1.0 / sqrt((double)SZ);
        for (unsigned m = t; m < 512u; m += 512u) {
            double a = 0.0;
            for (int k = 0; k < 9; ++k)
                if ((m >> k) & 1u) a += sh_feats[8 - k];
            double sp, cp;
            sincos(a, &sp, &cp);
            stage[1024u + m] = make_float2((float)(amp * cp), (float)(amp * sp));
        }
    }
    __syncthreads();

    unsigned ph = 0;

    #pragma unroll 1
    for (int l = 0; l <= 5; ++l) {
        const float2* Gl = &shG[l * NQ * 4];
        float2* obuf = (l & 1) ? P.buf1 : P.buf0;
        const float2* ibuf = (l & 1) ? P.buf0 : P.buf1;
        float2 r[4];

        // ---- Pass A_l: ring-gather + gates c0..c10; block = c11..c18 ----
        if (l == 0) {
            // FM product state at pinv(c): FM -> ring -> gates_0
            #pragma unroll
            for (int j = 0; j < 4; ++j) {
                unsigned li = (t << 2) | (unsigned)j;
                unsigned b = pinv(base | li);
                float2 e0 = stage[b & 1023u];
                float2 e1 = stage[1024u + (b >> 10)];
                r[j] = make_float2(e0.x * e1.x - e0.y * e1.y,
                                   e0.x * e1.y + e0.y * e1.x);
            }
        } else {
            // 2 contiguous 2048-amp source regions (one per c0)
            const unsigned R0 = pinv(base) & ~2047u;
            const unsigned R1 = pinv(base | 1u) & ~2047u;
            #pragma unroll
            for (int k = 0; k < 4; ++k) {
                unsigned i = ((unsigned)k << 10) | (t << 1);
                unsigned g = (i < 2048u) ? (R0 + i) : (R1 + (i - 2048u));
                *reinterpret_cast<float4*>(&stage[padl(i)]) =
                    *reinterpret_cast<const float4*>(&ibuf[g]);
            }
            __syncthreads();
            #pragma unroll
            for (int j = 0; j < 4; ++j) {
                unsigned li = (t << 2) | (unsigned)j;
                unsigned b = pinv(base | li);
                r[j] = stage[padl(((li & 1u) << 11) | (b & 2047u))];
            }
        }
        passA_tail(r, Gl, t, X0, stage);
        #pragma unroll
        for (int j = 0; j < 4; ++j)
            obuf[base | t | ((unsigned)j << 9)] = r[j];
        gridbar(P.ctr, (++ph) * NBLK);

        // ---- Pass B_l: gates c11..c18 in place; block = c bits 3..10 ----
        #pragma unroll
        for (int j = 0; j < 4; ++j) {
            unsigned li = (t & 7u) | ((unsigned)j << 3) | ((t >> 3) << 5);
            unsigned c = (li & 7u) | (blk << 3) | ((li >> 3) << 11);
            r[j] = obuf[c];
        }
        passB_gates(r, Gl, t, X0, stage);

        if (l == 5) {
            // fold final ring + <Z_0>: sum (-1)^{popc(c & 0x3FFFF)} |psi|^2
            double acc = 0.0;
            #pragma unroll
            for (int j = 0; j < 4; ++j) {
                unsigned li = t | ((unsigned)j << 9);
                unsigned c = (li & 7u) | (blk << 3) | ((li >> 3) << 11);
                float2 v = r[j];
                double w = (double)v.x * v.x + (double)v.y * v.y;
                acc += (__popc(c & 0x3FFFFu) & 1) ? -w : w;
            }
            sm[t] = acc;
            __syncthreads();
            for (int st = 256; st > 0; st >>= 1) {
                if ((int)t < st) sm[t] += sm[t + st];
                __syncthreads();
            }
            if (t == 0) P.partial[blk] = sm[0];
            // final arrive; non-zero blocks exit
            __syncthreads();
            if (t == 0) {
                __threadfence();
                __hip_atomic_fetch_add(P.ctr, 1u, __ATOMIC_RELAXED,
                                       __HIP_MEMORY_SCOPE_AGENT);
            }
            ++ph;
            if (blk != 0) return;
            if (t == 0) {
                while (__hip_atomic_load(P.ctr, __ATOMIC_RELAXED,
                                         __HIP_MEMORY_SCOPE_AGENT) < ph * NBLK)
                    __builtin_amdgcn_s_sleep(1);
                __threadfence();
            }
            __syncthreads();
        } else {
            #pragma unroll
            for (int j = 0; j < 4; ++j) {
                unsigned li = t | ((unsigned)j << 9);
                unsigned c = (li & 7u) | (blk << 3) | ((li >> 3) << 11);
                obuf[c] = r[j];
            }
            gridbar(P.ctr, (++ph) * NBLK);
        }
    }

    // ---- block 0: deterministic final sum of 256 partials ----
    sm[t] = (t < 256u) ? P.partial[t] : 0.0;
    __syncthreads();
    for (int st = 256; st > 0; st >>= 1) {
        if ((int)t < st) sm[t] += sm[t + st];
        __syncthreads();
    }
    if (t == 0) P.out[0] = (float)sm[0];
}

extern "C" void kernel_launch(void* const* d_in, const int* in_sizes, int n_in,
                              void* d_out, int out_size, void* d_ws, size_t ws_size,
                              hipStream_t stream)
{
    char* ws = (char*)d_ws;
    Params P;
    P.ei      = (const int*)d_in[0];
    P.state   = (const float*)d_in[1];
    P.mass    = (const float*)d_in[2];
    P.spin    = (const float*)d_in[3];
    P.charge  = (const float*)d_in[4];
    P.p_norm  = (const float*)d_in[5];
    P.theta   = (const float*)d_in[6];
    // d_in[7] = scattering (unused by reference)
    P.gnw     = (const float*)d_in[8];
    P.gnb     = (const float*)d_in[9];
    P.gew     = (const float*)d_in[10];
    P.geb     = (const float*)d_in[11];
    P.nw      = (const float*)d_in[12];
    P.nb      = (const float*)d_in[13];
    P.ew      = (const float*)d_in[14];
    P.eb      = (const float*)d_in[15];
    P.qw      = (const float*)d_in[16];
    P.partial = (double*)(ws + 16384);        // 2 KiB
    P.ctr     = (unsigned*)(ws + 20480);
    P.buf0    = (float2*)(ws + 32768);        // 4 MiB
    P.buf1    = P.buf0 + SZ;                  // 4 MiB
    P.out     = (float*)d_out;

    k_init<<<1, 1, 0, stream>>>(P.ctr);
    k_all<<<256, 512, 0, stream>>>(P);
}

// Round 11
// 110.464 us; speedup vs baseline: 3.2143x; 3.2143x over previous
//
#include <hip/hip_runtime.h>

#define NQ 19
#define SZ (1u << 19)

struct Params {
    const int* ei;
    const float* state; const float* mass; const float* spin; const float* charge;
    const float* p_norm; const float* theta;
    const float* gnw; const float* gnb; const float* gew; const float* geb;
    const float* nw; const float* nb; const float* ew; const float* eb;
    const float* qw;
    float2* buf0;
    unsigned* counter;
};

// Ring permutation inverse (bit space):
//   b = (c ^ (c>>1)) & 0x1FFFF ; b17 = c0^c17^c18 ; b18 = c0^c18
// Bits >=11 of pinv(c) depend ONLY on c0 and c bits 11..18.
__device__ __forceinline__ unsigned pinv(unsigned c)
{
    unsigned y = (c ^ (c >> 1)) & 0x1FFFFu;
    unsigned c0 = c & 1u, c17 = (c >> 17) & 1u, c18 = (c >> 18) & 1u;
    return y | ((c0 ^ c17 ^ c18) << 17) | ((c0 ^ c18) << 18);
}

// Padded LDS index: +2 float2 per 8 (keeps 8-groups intact; float4-safe).
__device__ __forceinline__ unsigned padl(unsigned l) { return l + 2u * (l >> 3); }

__device__ __forceinline__ void bfly(float2& a, float2& b,
                                     float2 u00, float2 u01,
                                     float2 u10, float2 u11)
{
    float2 na, nb;
    na.x = u00.x * a.x - u00.y * a.y + u01.x * b.x - u01.y * b.y;
    na.y = u00.x * a.y + u00.y * a.x + u01.x * b.y + u01.y * b.x;
    nb.x = u10.x * a.x - u10.y * a.y + u11.x * b.x - u11.y * b.y;
    nb.y = u10.x * a.y + u10.y * a.x + u11.x * b.y + u11.y * b.x;
    a = na;
    b = nb;
}

// Gates on register-index bits (r[4], jbit0..jbit0+n-1).
__device__ __forceinline__ void apply_gates(float2 r[4], const float2* Gl,
                                            int ampbit0, int jbit0, int n)
{
    #pragma unroll
    for (int k = 0; k < n; ++k) {
        const float2 u00 = Gl[(ampbit0 + k) * 4 + 0];
        const float2 u01 = Gl[(ampbit0 + k) * 4 + 1];
        const float2 u10 = Gl[(ampbit0 + k) * 4 + 2];
        const float2 u11 = Gl[(ampbit0 + k) * 4 + 3];
        const int m = 1 << (jbit0 + k);
        #pragma unroll
        for (int j = 0; j < 4; ++j)
            if (!(j & m)) bfly(r[j], r[j | m], u00, u01, u10, u11);
    }
}

// Cross-lane butterfly: gate on amp bit `ampbit` mapped to lane bit `lanebit`.
// No LDS, no barrier. side = my lane's value of that bit.
__device__ __forceinline__ void shfl_gate(float2 r[4], const float2* Gl,
                                          int ampbit, int lanebit)
{
    const float2 u00 = Gl[ampbit * 4 + 0], u01 = Gl[ampbit * 4 + 1];
    const float2 u10 = Gl[ampbit * 4 + 2], u11 = Gl[ampbit * 4 + 3];
    const int side = (threadIdx.x >> lanebit) & 1;
    const float2 u0 = side ? u10 : u00;
    const float2 u1 = side ? u11 : u01;
    #pragma unroll
    for (int j = 0; j < 4; ++j) {
        double d;
        __builtin_memcpy(&d, &r[j], 8);
        d = __shfl_xor(d, 1 << lanebit, 64);
        float2 p;
        __builtin_memcpy(&p, &d, 8);
        float2 a = side ? p : r[j];          // a = 0-side amp
        float2 b = side ? r[j] : p;          // b = 1-side amp
        float2 n;
        n.x = u0.x * a.x - u0.y * a.y + u1.x * b.x - u1.y * b.y;
        n.y = u0.x * a.y + u0.y * a.x + u1.x * b.y + u1.y * b.x;
        r[j] = n;
    }
}

// Build this layer's 19 gate matrices into LDS (one sincos per thread).
// Qubit q <-> bit k = 18-q. Fused gate U = RZ(t)*RX(t), c=cos(t/2), s=sin(t/2):
//   u00=(c^2,-sc) u01=(-s^2,-cs) u10=(s^2,-cs) u11=(c^2,sc)
__device__ __forceinline__ void build_G(float2* shG, const float* qw, int layer,
                                        unsigned t)
{
    if (t < NQ) {
        int k = (int)t, q = 18 - k;
        double th = (double)qw[(layer / 3) * (NQ * 3) + q * 3 + (layer % 3)];
        double c = cos(0.5 * th), s = sin(0.5 * th);
        shG[k * 4 + 0] = make_float2((float)(c * c), (float)(-s * c));
        shG[k * 4 + 1] = make_float2((float)(-s * s), (float)(-c * s));
        shG[k * 4 + 2] = make_float2((float)(s * s), (float)(-c * s));
        shG[k * 4 + 3] = make_float2((float)(c * c), (float)(s * c));
    }
}

// A-pass phase-1 tile index: li{0,1}=j, li{2..6}=lam0..4, li{8}=lam5,
// li{7}=hi0, li{9,10}=hi1,2.  Gates: c0,c1 regs; c2..c6,c8 shfl.
__device__ __forceinline__ unsigned liA1(unsigned lam, unsigned hi, unsigned j)
{
    return j | ((lam & 31u) << 2) | ((lam >> 5) << 8)
             | ((hi & 1u) << 7) | ((hi >> 1) << 9);
}
// A-pass phase-2: li{0..4}=lam0..4, li{7}=lam5, li{5,6}=hi0,1, li{8}=hi2,
// li{9,10}=j.  Gates: c7 shfl (lane bit 5); c9,c10 regs.
__device__ __forceinline__ unsigned liA2(unsigned lam, unsigned hi, unsigned j)
{
    return (lam & 31u) | ((lam >> 5) << 7) | ((hi & 3u) << 5)
         | ((hi >> 2) << 8) | (j << 9);
}
// A-pass tail: gates c0..c10 in 2 phases (1 LDS exchange, 1 barrier inside).
__device__ __forceinline__ void passA_tail(float2 r[4], const float2* shG,
                                           unsigned lam, unsigned hi, float2* X0)
{
    apply_gates(r, shG, 0, 0, 2);          // c0,c1
    shfl_gate(r, shG, 2, 0);               // c2..c6 on lane bits 0..4
    shfl_gate(r, shG, 3, 1);
    shfl_gate(r, shG, 4, 2);
    shfl_gate(r, shG, 5, 3);
    shfl_gate(r, shG, 6, 4);
    shfl_gate(r, shG, 8, 5);               // c8 on lane bit 5
    {
        unsigned lb = liA1(lam, hi, 0);    // thread's 4 li are consecutive
        *reinterpret_cast<float4*>(&X0[padl(lb)]) =
            make_float4(r[0].x, r[0].y, r[1].x, r[1].y);
        *reinterpret_cast<float4*>(&X0[padl(lb + 2u)]) =
            make_float4(r[2].x, r[2].y, r[3].x, r[3].y);
    }
    __syncthreads();
    #pragma unroll
    for (int j = 0; j < 4; ++j)
        r[j] = X0[padl(liA2(lam, hi, (unsigned)j))];
    shfl_gate(r, shG, 7, 5);               // c7 on lane bit 5
    apply_gates(r, shG, 9, 0, 2);          // c9,c10
}

// B-pass tile: li{0,1,2}=c0..c2, li{3..10}=c11..c18; block = c3..c10.
// Phase-1 li: li{0..2}=lam0..2, li{3,4}=j, li{5..7}=lam3..5, li{8..10}=hi.
__device__ __forceinline__ unsigned liB1(unsigned lam, unsigned hi, unsigned j)
{
    return (lam & 7u) | (j << 3) | (((lam >> 3) & 7u) << 5) | (hi << 8);
}
// Phase-2 li: li{0..4}=lam0..4, li{8}=lam5, li{5..7}=hi, li{9,10}=j.
__device__ __forceinline__ unsigned liB2(unsigned lam, unsigned hi, unsigned j)
{
    return (lam & 31u) | ((lam >> 5) << 8) | ((hi & 7u) << 5) | (j << 9);
}
__device__ __forceinline__ unsigned cB(unsigned li, unsigned blk)
{
    return (li & 7u) | (blk << 3) | ((li >> 3) << 11);
}

// ---------------------------------------------------------------------------
// k_A0: fused prep + layer-0 pass A. Per-block: GCN fp64 -> feats (t0),
// layer-0 G, FM phase tables W0[1024]/W1[512] in `stage`, then synthesize
// the post-ring FM state (FM -> ring -> gates_0) and apply gates c0..c10.
// Block 0 resets the done-counter used by k_B(l=5).
// ---------------------------------------------------------------------------
__global__ __launch_bounds__(512, 4)
void k_A0(Params P)
{
    __shared__ __align__(16) float2 stage[5120];   // W0[0..1024) W1[1024..1536)
    __shared__ __align__(16) float2 X0[2560];
    __shared__ float2 shG[NQ * 4];
    __shared__ double sh_feats[NQ];
    __shared__ double sh_S;

    const unsigned t = threadIdx.x;
    const unsigned lam = t & 63u, hi = t >> 6;
    const unsigned blk = blockIdx.x;
    const unsigned base = blk << 11;

    if (blk == 0 && t == 0) *P.counter = 0u;       // reset for k_B(l=5)

    if (t == 0) {
        double deg[8], dis[8], h[8], o1[8], he[8], o2[8];
        for (int v = 0; v < 8; ++v) deg[v] = 1.0;                 // self loops
        for (int e = 0; e < 8; ++e) deg[P.ei[8 + e]] += 1.0;
        for (int v = 0; v < 8; ++v) dis[v] = 1.0 / sqrt(deg[v]);
        for (int v = 0; v < 8; ++v) {
            double s = 0.0;
            for (int k = 0; k < 4; ++k)
                s += (double)P.state[v * 4 + k] * (double)P.gnw[k];
            h[v] = s;
        }
        for (int v = 0; v < 8; ++v) o1[v] = h[v] * dis[v] * dis[v] + (double)P.gnb[0];
        for (int e = 0; e < 8; ++e) {
            int s = P.ei[e], d = P.ei[8 + e];
            o1[d] += h[s] * dis[s] * dis[d];
        }
        for (int j = 0; j < 9; ++j) {
            double a = (double)P.nb[j];
            for (int v = 0; v < 8; ++v) a += o1[v] * (double)P.nw[v * 9 + j];
            sh_feats[j] = a;
        }
        for (int e = 0; e < 8; ++e)
            he[e] = (double)P.mass[e] * (double)P.gew[0]
                  + (double)P.spin[e] * (double)P.gew[1]
                  + (double)P.charge[e] * (double)P.gew[2];
        for (int v = 0; v < 8; ++v) o2[v] = he[v] * dis[v] * dis[v] + (double)P.geb[0];
        for (int e = 0; e < 8; ++e) {
            int s = P.ei[e], d = P.ei[8 + e];
            o2[d] += he[s] * dis[s] * dis[d];
        }
        for (int j = 0; j < 8; ++j) {
            double a = (double)P.eb[j];
            for (int v = 0; v < 8; ++v) a += o2[v] * (double)P.ew[v * 8 + j];
            sh_feats[9 + j] = a;
        }
        sh_feats[17] = (double)P.p_norm[0];
        sh_feats[18] = (double)P.theta[0];
        double S = 0.0;
        for (int q = 0; q < NQ; ++q) S += sh_feats[q];
        sh_S = S;
    }
    __syncthreads();

    build_G(shG, P.qw, 0, t);
    // FM tables: phi(b) = sum_k feats[18-k]*b_k - S/2; amp in W1
    {
        double S = sh_S;
        for (unsigned m = t; m < 1024u; m += 512u) {
            double a = -0.5 * S;
            for (int k = 0; k < 10; ++k)
                if ((m >> k) & 1u) a += sh_feats[18 - k];
            double sp, cp;
            sincos(a, &sp, &cp);
            stage[m] = make_float2((float)cp, (float)sp);
        }
        const double amp = 1.0 / sqrt((double)SZ);
        for (unsigned m = t; m < 512u; m += 512u) {
            double a = 0.0;
            for (int k = 0; k < 9; ++k)
                if ((m >> k) & 1u) a += sh_feats[8 - k];
            double sp, cp;
            sincos(a, &sp, &cp);
            stage[1024u + m] = make_float2((float)(amp * cp), (float)(amp * sp));
        }
    }
    __syncthreads();

    float2 r[4];
    #pragma unroll
    for (int j = 0; j < 4; ++j) {
        unsigned li = liA1(lam, hi, (unsigned)j);
        unsigned b = pinv(base | li);
        float2 e0 = stage[b & 1023u];
        float2 e1 = stage[1024u + (b >> 10)];
        r[j] = make_float2(e0.x * e1.x - e0.y * e1.y,
                           e0.x * e1.y + e0.y * e1.x);
    }
    passA_tail(r, shG, lam, hi, X0);
    #pragma unroll
    for (int j = 0; j < 4; ++j)
        P.buf0[base | liA2(lam, hi, (unsigned)j)] = r[j];
}

// ---------------------------------------------------------------------------
// k_A (layers 1..5): ring-gather (coalesced 2-region staging) + gates c0..c10.
// 256 blocks x 512 threads; block = c bits 11..18. 2 phases, 2 barriers.
// ---------------------------------------------------------------------------
__global__ __launch_bounds__(512, 4)
void k_A(const float2* __restrict__ in, float2* __restrict__ out,
         const float* __restrict__ qw, int layer)
{
    __shared__ __align__(16) float2 stage[5120];
    __shared__ __align__(16) float2 X0[2560];
    __shared__ float2 shG[NQ * 4];
    const unsigned t = threadIdx.x;
    const unsigned lam = t & 63u, hi = t >> 6;
    const unsigned base = blockIdx.x << 11;

    // prefetch the 2 contiguous source regions first (latency overlaps build_G)
    const unsigned R0 = pinv(base) & ~2047u;
    const unsigned R1 = pinv(base | 1u) & ~2047u;
    float4 v[4];
    #pragma unroll
    for (int k = 0; k < 4; ++k) {
        unsigned i = ((unsigned)k << 10) | (t << 1);
        unsigned g = (i < 2048u) ? (R0 + i) : (R1 + (i - 2048u));
        v[k] = *reinterpret_cast<const float4*>(&in[g]);
    }
    build_G(shG, qw, layer, t);
    #pragma unroll
    for (int k = 0; k < 4; ++k) {
        unsigned i = ((unsigned)k << 10) | (t << 1);
        *reinterpret_cast<float4*>(&stage[padl(i)]) = v[k];
    }
    __syncthreads();

    float2 r[4];
    #pragma unroll
    for (int j = 0; j < 4; ++j) {
        unsigned li = liA1(lam, hi, (unsigned)j);
        unsigned b = pinv(base | li);
        r[j] = stage[padl(((li & 1u) << 11) | (b & 2047u))];
    }
    passA_tail(r, shG, lam, hi, X0);
    #pragma unroll
    for (int j = 0; j < 4; ++j)
        out[base | liA2(lam, hi, (unsigned)j)] = r[j];
}

// ---------------------------------------------------------------------------
// k_B: gates c11..c18 in place; block = c bits 3..10 (64B runs). 2 phases,
// 2 barriers. do_reduce (layer 5): fold final ring + <Z_0> into sign-twisted
// fp64 partials; last-done block sums partial[0..255] in order.
// ---------------------------------------------------------------------------
__global__ __launch_bounds__(512, 4)
void k_B(float2* __restrict__ buf, const float* __restrict__ qw, int layer,
         int do_reduce, double* __restrict__ partial,
         unsigned* __restrict__ counter, float* __restrict__ out)
{
    __shared__ __align__(16) float2 X0[2560];
    __shared__ double sm[512];
    __shared__ float2 shG[NQ * 4];
    __shared__ int who;
    const unsigned t = threadIdx.x;
    const unsigned lam = t & 63u, hi = t >> 6;
    const unsigned blk = blockIdx.x;

    float2 r[4];
    #pragma unroll
    for (int j = 0; j < 4; ++j)
        r[j] = buf[cB(liB1(lam, hi, (unsigned)j), blk)];
    build_G(shG, qw, layer, t);
    __syncthreads();

    apply_gates(r, shG, 11, 0, 2);         // c11,c12
    shfl_gate(r, shG, 13, 3);              // c13..c15 on lane bits 3..5
    shfl_gate(r, shG, 14, 4);
    shfl_gate(r, shG, 15, 5);
    #pragma unroll
    for (int j = 0; j < 4; ++j)
        X0[padl(liB1(lam, hi, (unsigned)j))] = r[j];
    __syncthreads();
    #pragma unroll
    for (int j = 0; j < 4; ++j)
        r[j] = X0[padl(liB2(lam, hi, (unsigned)j))];
    shfl_gate(r, shG, 16, 5);              // c16 on lane bit 5
    apply_gates(r, shG, 17, 0, 2);         // c17,c18

    if (do_reduce) {
        double acc = 0.0;
        #pragma unroll
        for (int j = 0; j < 4; ++j) {
            unsigned c = cB(liB2(lam, hi, (unsigned)j), blk);
            float2 v = r[j];
            double w = (double)v.x * v.x + (double)v.y * v.y;
            acc += (__popc(c & 0x3FFFFu) & 1) ? -w : w;
        }
        sm[t] = acc;
        __syncthreads();
        for (int st = 256; st > 0; st >>= 1) {
            if ((int)t < st) sm[t] += sm[t + st];
            __syncthreads();
        }
        if (t == 0) {
            partial[blk] = sm[0];
            __threadfence();
            unsigned old = atomicAdd(counter, 1u);
            who = (old == 255u);
        }
        __syncthreads();
        if (who) {
            double v = (t < 256u)
                ? __hip_atomic_load(&partial[t], __ATOMIC_RELAXED,
                                    __HIP_MEMORY_SCOPE_AGENT)
                : 0.0;
            sm[t] = v;
            __syncthreads();
            for (int st = 256; st > 0; st >>= 1) {
                if ((int)t < st) sm[t] += sm[t + st];
                __syncthreads();
            }
            if (t == 0) out[0] = (float)sm[0];
        }
    } else {
        #pragma unroll
        for (int j = 0; j < 4; ++j)
            buf[cB(liB2(lam, hi, (unsigned)j), blk)] = r[j];
    }
}

extern "C" void kernel_launch(void* const* d_in, const int* in_sizes, int n_in,
                              void* d_out, int out_size, void* d_ws, size_t ws_size,
                              hipStream_t stream)
{
    char* ws = (char*)d_ws;
    double*   partial = (double*)(ws + 16384);        // 2 KiB
    unsigned* counter = (unsigned*)(ws + 20480);
    float2*   buf0    = (float2*)(ws + 32768);        // 4 MiB
    float2*   buf1    = buf0 + SZ;                    // 4 MiB
    const float* qw   = (const float*)d_in[16];
    float* out        = (float*)d_out;

    Params P;
    P.ei      = (const int*)d_in[0];
    P.state   = (const float*)d_in[1];
    P.mass    = (const float*)d_in[2];
    P.spin    = (const float*)d_in[3];
    P.charge  = (const float*)d_in[4];
    P.p_norm  = (const float*)d_in[5];
    P.theta   = (const float*)d_in[6];
    // d_in[7] = scattering (unused by reference)
    P.gnw     = (const float*)d_in[8];
    P.gnb     = (const float*)d_in[9];
    P.gew     = (const float*)d_in[10];
    P.geb     = (const float*)d_in[11];
    P.nw      = (const float*)d_in[12];
    P.nb      = (const float*)d_in[13];
    P.ew      = (const float*)d_in[14];
    P.eb      = (const float*)d_in[15];
    P.qw      = qw;
    P.buf0    = buf0;
    P.counter = counter;

    k_A0<<<256, 512, 0, stream>>>(P);
    k_B<<<256, 512, 0, stream>>>(buf0, qw, 0, 0, partial, counter, out);
    for (int l = 1; l <= 5; ++l) {
        float2* in  = (l & 1) ? buf0 : buf1;
        float2* o   = (l & 1) ? buf1 : buf0;
        k_A<<<256, 512, 0, stream>>>(in, o, qw, l);
        k_B<<<256, 512, 0, stream>>>(o, qw, l, l == 5, partial, counter, out);
    }
}